// Round 7
// baseline (90.642 us; speedup 1.0000x reference)
//
#include <hip/hip_runtime.h>
#include <math.h>

#define PI_D 3.14159265358979323846
#define PIF  3.14159265358979323846f
#define NLAT 128
#define NLON 256
#define LMAX 50
#define MMAX 50
#define NPTS 2048
#define NBT 16
#define NBA 32
#define NBIN (NBT * NBA)
#define WBIN 0.19634954084936207f   /* pi/16 */
#define INVW 5.092958178940651f     /* 16/pi */
#define BIG 1e30f
#define KMASK 0xFFFFF800u           /* high 21 bits of distance, low 11 = index */

__device__ __forceinline__ void insert3(float kf, float& k0, float& k1, float& k2) {
    float n1 = __builtin_amdgcn_fmed3f(kf, k0, k1);
    float n2 = __builtin_amdgcn_fmed3f(kf, k1, k2);
    k0 = fminf(kf, k0);
    k1 = n1;
    k2 = n2;
}

__device__ __forceinline__ float mkkey(float gt, float gl, float2 tl, int idx) {
    float dt = gt - tl.x, dl = gl - tl.y;
    float d = fmaf(dt, dt, dl * dl);
    return __uint_as_float((__float_as_uint(d) & KMASK) | (unsigned)idx);
}

// ---------------------------------------------------------------------------
// Kernel 1 (fused): blocks 0..511  = binned knn + interp + DFT (one field,lat)
//                   blocks 512..639 = PCTW column k = bid-512 (lane = m).
//                   Block 512 zeroes out[0] for kernel 2's atomics.
// ---------------------------------------------------------------------------
__global__ __launch_bounds__(256) void fused_main(
    const float* __restrict__ pred, const float* __restrict__ tgt,
    float* __restrict__ pctwT, float* __restrict__ fre, float* __restrict__ out) {

    __shared__ float2 s_btl[NPTS];     // (theta, az) in bin order   16 KB
    __shared__ float  s_br[NPTS];      // radius in bin order         8 KB
    __shared__ int    s_cnt[NBIN];     // counts, then scatter cursor 2 KB
    __shared__ int    s_off[NBIN + 1]; // bin start offsets           2 KB
    __shared__ float  ctab[NLON];
    __shared__ float  row[NLON];
    __shared__ float  part[200];

    int bid = blockIdx.x;
    int t = threadIdx.x;

    if (bid >= 512) {
        // ---------------- PCTW role: one k-column, lane = m ----------------
        int k = bid - 512;                       // 0..127
        if (k == 0 && t == 0) out[0] = 0.0f;     // init for contract's atomics
        if (t < MMAX) {
            int m = t;
            double theta = PI_D * (double)k / 127.0;
            double cost = cos(theta);
            double sint = sqrt(fmax(1.0 - cost * cost, 0.0));
            // Clenshaw-Curtis weight via Chebyshev recurrence (Nn=127, odd)
            double c2 = cos(2.0 * theta);
            double two_c2 = 2.0 * c2;
            double cp = 1.0, cc = c2, v = 0.0;
            for (int tt = 1; tt <= 63; ++tt) {
                v += 2.0 * cc / (double)(4 * tt * tt - 1);
                double cn = two_c2 * cc - cp;
                cp = cc;
                cc = cn;
            }
            double w = (2.0 / 127.0) * (1.0 - v);
            if (k == 0 || k == 127) w *= 0.5;

            double pmm = sqrt(1.0 / (4.0 * PI_D));
            for (int i = 1; i <= m; ++i)
                pmm = -pmm * sqrt((2.0 * (double)i + 1.0) / (2.0 * (double)i)) * sint;

            float* o = pctwT + (size_t)k * MMAX + m;  // pctwT[(l*NLAT+k)*MMAX+m]
            for (int l = 0; l < m; ++l) o[(size_t)l * NLAT * MMAX] = 0.0f;
            o[(size_t)m * NLAT * MMAX] = (float)(pmm * w);
            double plm2 = pmm, plm1 = 0.0;
            if (m + 1 < LMAX) {
                plm1 = sqrt(2.0 * (double)m + 3.0) * cost * pmm;
                o[(size_t)(m + 1) * NLAT * MMAX] = (float)(plm1 * w);
            }
            for (int l = m + 2; l < LMAX; ++l) {
                double ll = (double)l;
                double denom = ll * ll - (double)(m * m);
                double a = sqrt((4.0 * ll * ll - 1.0) / denom);
                double b = sqrt(((2.0 * ll + 1.0) * (double)(l - 1 + m) * (double)(l - 1 - m)) /
                                ((2.0 * ll - 3.0) * denom));
                double p = a * cost * plm1 - b * plm2;
                o[(size_t)l * NLAT * MMAX] = (float)(p * w);
                plm2 = plm1;
                plm1 = p;
            }
        }
        return;
    }

    // ---------------- KNN role ----------------
    int f = bid >> 7;
    int lat = bid & 127;
    const float* src = ((f < 2) ? pred : tgt) + (size_t)(f & 1) * NPTS * 3;

    s_cnt[t] = 0;
    s_cnt[t + 256] = 0;
    ctab[t] = (float)cos(2.0 * PI_D * (double)t / (double)NLON);
    __syncthreads();

    // to_spherical into registers (exact reference fp order) + bin counts
    float pth[8], paz[8], pr[8];
    int pbin[8];
#pragma unroll
    for (int i = 0; i < 8; ++i) {
        int n = t + 256 * i;
        float x = src[3 * n], y = src[3 * n + 1], z = src[3 * n + 2];
        float s1 = z * z;
        float s2 = s1 + y * y;
        float s3 = s2 + x * x;
        float r = sqrtf(s3);
        float rho = sqrtf(s2);
        float th = acosf(x / r);
        float a = acosf(y / rho);
        float az = (z < 0.0f) ? (a + (2.0f * PIF - 2.0f * a)) : a;
        az -= PIF;
        int bt = min(max((int)(th * INVW), 0), NBT - 1);
        int ba = min(max((int)((az + PIF) * INVW), 0), NBA - 1);
        int b = bt * NBA + ba;
        pth[i] = th; paz[i] = az; pr[i] = r; pbin[i] = b;
        atomicAdd(&s_cnt[b], 1);
    }
    __syncthreads();

    // exclusive scan of 512 counts by one wave (8 bins per lane)
    if (t == 0) s_off[NBIN] = NPTS;
    if (t < 64) {
        int base = t * 8;
        int loc[8];
        int run = 0;
#pragma unroll
        for (int i = 0; i < 8; ++i) { loc[i] = run; run += s_cnt[base + i]; }
        int x = run;
#pragma unroll
        for (int d = 1; d < 64; d <<= 1) {
            int y = __shfl_up(x, d);
            if (t >= d) x += y;
        }
        int ex = x - run;
#pragma unroll
        for (int i = 0; i < 8; ++i) s_off[base + i] = ex + loc[i];
    }
    __syncthreads();
    s_cnt[t] = s_off[t];
    s_cnt[t + 256] = s_off[t + 256];
    __syncthreads();
#pragma unroll
    for (int i = 0; i < 8; ++i) {
        int pos = atomicAdd(&s_cnt[pbin[i]], 1);
        s_btl[pos] = make_float2(pth[i], paz[i]);
        s_br[pos] = pr[i];
    }
    __syncthreads();

    // ---- 3-NN query: one grid point per thread, packed keys ----
    int j = t;
    float gt = (float)((double)lat * PI_D / 128.0);
    float gl = (float)(((double)j - 128.0) * PI_D / 128.0);
    float glp = gl + PIF;
    int bt0 = lat >> 3;     // block-uniform
    int ba0 = j >> 3;

    // contiguous-segment scanner, x4 unrolled so LDS loads pipeline
    auto scan_seg = [&](int i, int i1, float& q0, float& q1, float& q2) {
        for (; i + 4 <= i1; i += 4) {
            float2 a0 = s_btl[i];
            float2 a1 = s_btl[i + 1];
            float2 a2 = s_btl[i + 2];
            float2 a3 = s_btl[i + 3];
            insert3(mkkey(gt, gl, a0, i), q0, q1, q2);
            insert3(mkkey(gt, gl, a1, i + 1), q0, q1, q2);
            insert3(mkkey(gt, gl, a2, i + 2), q0, q1, q2);
            insert3(mkkey(gt, gl, a3, i + 3), q0, q1, q2);
        }
        for (; i < i1; ++i)
            insert3(mkkey(gt, gl, s_btl[i], i), q0, q1, q2);
    };

    float k0 = BIG, k1 = BIG, k2 = BIG;

    // initial 3x3-bin pass: <=3 uniform row iterations, contiguous segments
    {
        int rtl = max(bt0 - 1, 0), rth = min(bt0 + 1, NBT - 1);
        int bal = max(ba0 - 1, 0), bah = min(ba0 + 1, NBA - 1);
        for (int bt = rtl; bt <= rth; ++bt)
            scan_seg(s_off[bt * NBA + bal], s_off[bt * NBA + bah + 1], k0, k1, k2);
    }

    // safe-radius check after the 3x3 pass
    bool done;
    {
        float safe = BIG;
        if (bt0 - 1 > 0)       safe = fminf(safe, gt - (float)(bt0 - 1) * WBIN);
        if (bt0 + 1 < NBT - 1) safe = fminf(safe, (float)(bt0 + 2) * WBIN - gt);
        if (ba0 - 1 > 0)       safe = fminf(safe, glp - (float)(ba0 - 1) * WBIN);
        if (ba0 + 1 < NBA - 1) safe = fminf(safe, (float)(ba0 + 2) * WBIN - glp);
        done = (k2 <= safe * safe);
    }

    // fallback: RESET selection and expand by full theta-rows (contiguous,
    // sparse near poles where this path triggers). az never constrains since
    // whole rows are scanned; no duplicate inserts since each row scanned once.
    if (__any(!done)) {
        float q0 = BIG, q1 = BIG, q2 = BIG;
        int lo = bt0, hi = bt0;
        scan_seg(s_off[bt0 * NBA], s_off[(bt0 + 1) * NBA], q0, q1, q2);
        while (true) {
            float safe = BIG;
            if (lo > 0)       safe = fminf(safe, gt - (float)lo * WBIN);
            if (hi < NBT - 1) safe = fminf(safe, (float)(hi + 1) * WBIN - gt);
            if (__all(q2 <= safe * safe)) break;
            if (lo == 0 && hi == NBT - 1) break;
            if (lo > 0) {
                --lo;
                scan_seg(s_off[lo * NBA], s_off[(lo + 1) * NBA], q0, q1, q2);
            }
            if (hi < NBT - 1) {
                ++hi;
                scan_seg(s_off[hi * NBA], s_off[(hi + 1) * NBA], q0, q1, q2);
            }
        }
        if (!done) { k0 = q0; k1 = q1; k2 = q2; }
    }

    // epilogue: indices from keys, exact distances, interp weights
    {
        int i0 = __float_as_uint(k0) & 0x7FF;
        int i1 = __float_as_uint(k1) & 0x7FF;
        int i2 = __float_as_uint(k2) & 0x7FF;
        float2 p0 = s_btl[i0];
        float2 p1 = s_btl[i1];
        float2 p2 = s_btl[i2];
        float dt0 = gt - p0.x, dl0 = gl - p0.y;
        float dt1 = gt - p1.x, dl1 = gl - p1.y;
        float dt2 = gt - p2.x, dl2 = gl - p2.y;
        float d0 = fmaf(dt0, dt0, dl0 * dl0);
        float d1 = fmaf(dt1, dt1, dl1 * dl1);
        float d2 = fmaf(dt2, dt2, dl2 * dl2);
        float s = d0 + d1 + d2;
        row[j] = (d0 * s_br[i0] + d1 * s_br[i1] + d2 * s_br[i2]) / s;
    }
    __syncthreads();

    // DFT of the row: 50 modes x 4 partial sums of 64 (threads 0..199)
    if (t < 200) {
        int mm = t >> 2, q = t & 3;
        int bs = q * 64;
        float acc = 0.0f;
        int p = (bs * mm) & (NLON - 1);
        for (int i = 0; i < 64; ++i) {
            acc += row[bs + i] * ctab[p];
            p = (p + mm) & (NLON - 1);
        }
        part[t] = acc;
    }
    __syncthreads();
    if (t < MMAX) {
        const float* pp = part + t * 4;
        fre[(f * NLAT + lat) * MMAX + t] =
            ((pp[0] + pp[1]) + (pp[2] + pp[3])) * (float)(2.0 * PI_D / (double)NLON);
    }
}

// ---------------------------------------------------------------------------
// Kernel 2: Legendre contraction + loss. Block per (b,l); 256 threads =
// (mm 0..63) x (k-quarter 0..3); LDS reduce; one atomic per block.
// ---------------------------------------------------------------------------
__global__ __launch_bounds__(256) void contract_loss(const float* __restrict__ fre,
                                                     const float* __restrict__ pctwT,
                                                     float* __restrict__ out) {
    int b = blockIdx.x / LMAX;
    int l = blockIdx.x % LMAX;
    int mm = threadIdx.x & 63;
    int kq = threadIdx.x >> 6;
    __shared__ float sp[4][64], st_[4][64];
    float pc = 0.0f, tc = 0.0f;
    if (mm < MMAX) {
        const float* pw = pctwT + ((size_t)l * NLAT + kq * 32) * MMAX + mm;
        const float* fp = fre + ((size_t)b * NLAT + kq * 32) * MMAX + mm;
        const float* ft = fre + ((size_t)(2 + b) * NLAT + kq * 32) * MMAX + mm;
#pragma unroll 8
        for (int k = 0; k < 32; ++k) {
            float w = pw[k * MMAX];
            pc += fp[k * MMAX] * w;
            tc += ft[k * MMAX] * w;
        }
    }
    sp[kq][mm] = pc;
    st_[kq][mm] = tc;
    __syncthreads();
    if (threadIdx.x < 64) {
        int m2 = threadIdx.x;
        float pcs = (sp[0][m2] + sp[1][m2]) + (sp[2][m2] + sp[3][m2]);
        float tcs = (st_[0][m2] + st_[1][m2]) + (st_[2][m2] + st_[3][m2]);
        float diff = pcs - tcs;
        double dl_ = (double)(49 - l);
        float rw = (float)exp(-(dl_ * dl_) / 5000.0);
        float contrib = (m2 < MMAX) ? diff * diff * rw * 0.5f : 0.0f;
        for (int off = 32; off > 0; off >>= 1) contrib += __shfl_down(contrib, off);
        if (m2 == 0) atomicAdd(out, contrib);
    }
}

// ---------------------------------------------------------------------------
extern "C" void kernel_launch(void* const* d_in, const int* in_sizes, int n_in,
                              void* d_out, int out_size, void* d_ws, size_t ws_size,
                              hipStream_t stream) {
    const float* pred = (const float*)d_in[0];
    const float* tgt = (const float*)d_in[1];
    float* ws = (float*)d_ws;

    float* pctwT = ws;            // 50*128*50 = 320000 floats
    float* fre   = ws + 320000;   // 4*128*50  =  25600 floats
    float* out = (float*)d_out;

    fused_main<<<640, 256, 0, stream>>>(pred, tgt, pctwT, fre, out);
    contract_loss<<<2 * LMAX, 256, 0, stream>>>(fre, pctwT, out);
}